// Round 10
// baseline (215.479 us; speedup 1.0000x reference)
//
#include <hip/hip_runtime.h>

#define NROWS  65536
#define CDIM   128
#define MKEYS  1024
#define BROWS  256    // rows per block
#define TROWS  16     // rows per tile
#define NTILES 16
#define CANDCAP 32

typedef _Float16 half8 __attribute__((ext_vector_type(8)));
typedef _Float16 half4 __attribute__((ext_vector_type(4)));
typedef float    floatx4 __attribute__((ext_vector_type(4)));

union FU { float f; unsigned u; };

#define MFMA16 __builtin_amdgcn_mfma_f32_16x16x32_f16

// ---------------- Kernel A: convert keys fp32 -> fp16 in MFMA-fragment order --------
// Layout: for key k, dim d:  g=k>>4, n=k&15, f=d>>5, q8=(d&31)>>3, e=d&7
//   kh[ ((g*4+f)*64 + q8*16 + n)*8 + e ] = (fp16) keys[k][d]
// Fragment (g,f): kh + (g*4+f)*512 + lane*8  -> 64 lanes x 16B contiguous.
__global__ __launch_bounds__(256) void cvt_keys_kernel(const float* __restrict__ keys,
                                                       _Float16* __restrict__ kh) {
    int i  = blockIdx.x * 256 + threadIdx.x;        // 32768 threads
    int k  = i >> 5;                                // key 0..1023
    int d0 = (i & 31) * 4;                          // dim 0,4,...,124
    float4 f4 = *(const float4*)(keys + (long)k * CDIM + d0);
    half4 hv;
    hv[0] = (_Float16)f4.x; hv[1] = (_Float16)f4.y;
    hv[2] = (_Float16)f4.z; hv[3] = (_Float16)f4.w;
    int g = k >> 4, n = k & 15;
    int f = d0 >> 5, q8 = (d0 & 31) >> 3, e = d0 & 7;
    long idx = ((long)((g * 4 + f) * 64 + q8 * 16 + n)) * 8 + e;
    *(half4*)(kh + idx) = hv;
}

// ---------------- Kernel B: keys-in-registers, 16 waves/block (R10) ------------------
// 256 blocks (1/CU) x 16 waves x 64 keys/wave (16 half8 = 64 VGPR, loaded once).
// Per 16-row tile: prefetched q-tile (regs->LDS double buffer), pass1 register-MFMA
// -> M1 -> thr = M1-2e1-slack (computed redundantly by all threads), pass2
// bit-identical recompute pushes ALL keys >= thr. cnt==1 -> exact argmax; cnt>1 ->
// exact fp32 rescore (lowest-key ties); overflow -> exact full rescan. 4 barriers/tile.
__global__ __launch_bounds__(1024, 4) void gather_main(
    const float* __restrict__ q,      // trend_representation (65536x128)
    const float* __restrict__ rep,    // representation
    const float* __restrict__ keys,   // fp32 keys (1024x128)
    const float* __restrict__ vals,   // fp32 values
    const _Float16* __restrict__ kh,  // fp16 keys, fragment order (ws)
    float* __restrict__ out)          // [131072]: keys_g then values_g
{
    __shared__ _Float16 qh[2][TROWS][128];         // 8 KB double-buffered q-tile
    __shared__ float qss[TROWS][17];               // per-(row,c8) sumsq
    __shared__ float wtv[16][TROWS];               // per-wave per-row max
    __shared__ int   candCnt[2][TROWS];
    __shared__ int   candKey[2][TROWS][CANDCAP];   // 4 KB
    __shared__ int   rowOvf[2][TROWS];
    __shared__ unsigned long long rowBest[2][TROWS];
    __shared__ int   rowIdxAll[BROWS];             // 1 KB

    const int t    = threadIdx.x;     // 0..1023
    const int w    = t >> 6;          // wave 0..15 (owns keys w*64..w*64+63)
    const int lane = t & 63;
    const int n    = lane & 15;       // q-row (C col) in tile
    const int quad = lane >> 4;       // key sub-slice / C row group
    const long blk0 = (long)blockIdx.x * BROWS;

    // ---- preload this wave's 64 keys into 16 half8 registers (one burst) ----
    const _Float16* kb = kh + (long)w * 8192 + lane * 8;
    half8 k00,k01,k02,k03, k10,k11,k12,k13, k20,k21,k22,k23, k30,k31,k32,k33;
#define KL(g) \
    k##g##0 = *(const half8*)(kb + (g)*2048 +    0); \
    k##g##1 = *(const half8*)(kb + (g)*2048 +  512); \
    k##g##2 = *(const half8*)(kb + (g)*2048 + 1024); \
    k##g##3 = *(const half8*)(kb + (g)*2048 + 1536);
    KL(0) KL(1) KL(2) KL(3)

#define ENCMAX(v_, key_, dst_) {                                           \
        FU su; su.f = (v_);                                                \
        unsigned ord = (su.u & 0x80000000u) ? ~su.u : (su.u | 0x80000000u);\
        unsigned long long enc = ((unsigned long long)ord << 32)           \
                               | (unsigned)(1023 - (key_));                \
        atomicMax(&rowBest[p][dst_], enc); }

    // ---- prologue: prefetch tile-0 q into registers ----
    float4 pa, pb;
    if (t < 256) {
        int row = t >> 4, c8 = t & 15;
        const float4* src = (const float4*)(q + (blk0 + row) * CDIM + c8 * 8);
        pa = src[0]; pb = src[1];
    }

    for (int tile = 0; tile < NTILES; ++tile) {
        const int p = tile & 1;
        const long g0 = blk0 + (long)tile * TROWS;

        // ---- stage-write: regs -> qh[p] (swizzled) + qss; reset state[p] ----
        if (t < 256) {
            int row = t >> 4, c8 = t & 15;
            qss[row][c8] = pa.x*pa.x + pa.y*pa.y + pa.z*pa.z + pa.w*pa.w
                         + pb.x*pb.x + pb.y*pb.y + pb.z*pb.z + pb.w*pb.w;
            half8 hv;
            hv[0] = (_Float16)pa.x; hv[1] = (_Float16)pa.y;
            hv[2] = (_Float16)pa.z; hv[3] = (_Float16)pa.w;
            hv[4] = (_Float16)pb.x; hv[5] = (_Float16)pb.y;
            hv[6] = (_Float16)pb.z; hv[7] = (_Float16)pb.w;
            int phys = c8 ^ (row & 7);
            *(half8*)&qh[p][row][phys * 8] = hv;
        } else if (t >= 256 && t < 256 + TROWS) {
            int r = t - 256;
            candCnt[p][r] = 0; rowOvf[p][r] = 0; rowBest[p][r] = 0ull;
        }
        __syncthreads();                                   // B1

        // ---- prefetch next q-tile (hidden under pass1/pass2 MFMA) ----
        if (t < 256 && tile + 1 < NTILES) {
            int row = t >> 4, c8 = t & 15;
            const float4* src = (const float4*)(q + (g0 + TROWS + row) * CDIM + c8 * 8);
            pa = src[0]; pb = src[1];
        }

        // ---- B-fragments for row n ----
        int x = n & 7;
        half8 qf0 = *(const half8*)&qh[p][n][((0 * 4 + quad) ^ x) * 8];
        half8 qf1 = *(const half8*)&qh[p][n][((1 * 4 + quad) ^ x) * 8];
        half8 qf2 = *(const half8*)&qh[p][n][((2 * 4 + quad) ^ x) * 8];
        half8 qf3 = *(const half8*)&qh[p][n][((3 * 4 + quad) ^ x) * 8];

        // ---- pass 1: per-lane max over this wave's 64 keys ----
        float m1 = -3.4e38f;
#define P1G(g) { floatx4 acc = {0.f,0.f,0.f,0.f};                        \
        acc = MFMA16(k##g##0, qf0, acc, 0, 0, 0);                        \
        acc = MFMA16(k##g##1, qf1, acc, 0, 0, 0);                        \
        acc = MFMA16(k##g##2, qf2, acc, 0, 0, 0);                        \
        acc = MFMA16(k##g##3, qf3, acc, 0, 0, 0);                        \
        m1 = fmaxf(m1, fmaxf(fmaxf(acc[0], acc[1]), fmaxf(acc[2], acc[3]))); }
        P1G(0) P1G(1) P1G(2) P1G(3)
        m1 = fmaxf(m1, __shfl_xor(m1, 16));
        m1 = fmaxf(m1, __shfl_xor(m1, 32));
        if (lane < TROWS) wtv[w][n] = m1;
        __syncthreads();                                   // B2

        // ---- threshold (computed redundantly by every thread for its row n) ----
        float M1 = wtv[0][n];
        #pragma unroll
        for (int ww = 1; ww < 16; ++ww) M1 = fmaxf(M1, wtv[ww][n]);
        float qn2 = 0.f;
        #pragma unroll
        for (int j = 0; j < 16; ++j) qn2 += qss[n][j];
        // fp16 rounding: |s~ - s| <= 2^-10*1.01*||q||*||k||max(<=17) + slack
        float thr = M1 - 2.f * (0.0168f * sqrtf(qn2) + 0.002f) - 0.02f;

        // ---- pass 2: bit-identical recompute; push ALL keys >= thr ----
#define PUSHK(K_) { int pp = atomicAdd(&candCnt[p][n], 1);               \
        if (pp < CANDCAP) candKey[p][n][pp] = (K_); else rowOvf[p][n] = 1; }
#define P2G(g) { floatx4 acc = {0.f,0.f,0.f,0.f};                        \
        acc = MFMA16(k##g##0, qf0, acc, 0, 0, 0);                        \
        acc = MFMA16(k##g##1, qf1, acc, 0, 0, 0);                        \
        acc = MFMA16(k##g##2, qf2, acc, 0, 0, 0);                        \
        acc = MFMA16(k##g##3, qf3, acc, 0, 0, 0);                        \
        int keyb = ((w * 4 + (g)) << 4) + (quad << 2);                   \
        if (acc[0] >= thr) PUSHK(keyb);                                  \
        if (acc[1] >= thr) PUSHK(keyb + 1);                              \
        if (acc[2] >= thr) PUSHK(keyb + 2);                              \
        if (acc[3] >= thr) PUSHK(keyb + 3); }
        P2G(0) P2G(1) P2G(2) P2G(3)
        __syncthreads();                                   // B3

        // ---- sole candidate == exact argmax ----
        if (t < TROWS) {
            if (!rowOvf[p][t] && candCnt[p][t] == 1)
                rowIdxAll[tile * TROWS + t] = candKey[p][t][0];
        }
        // ---- exact fp32 rescore: 64 groups of 16 lanes, coalesced 512B dots ----
        {
            int grp = t >> 4, l16 = t & 15;
            #pragma unroll 1
            for (int sweep = 0; sweep < 8; ++sweep) {
                int item = sweep * 64 + grp;      // 16 rows x 32 slots
                int row = item >> 5, slot = item & 31;
                int cnt = candCnt[p][row];
                if (!rowOvf[p][row] && cnt > 1 && slot < cnt) {
                    int key = candKey[p][row][slot];
                    const float* qp  = q + (g0 + row) * CDIM + l16 * 8;
                    const float* kp2 = keys + (long)key * CDIM + l16 * 8;
                    float4 xa = *(const float4*)(qp),  xb = *(const float4*)(qp + 4);
                    float4 ya = *(const float4*)(kp2), yb = *(const float4*)(kp2 + 4);
                    float v = xa.x*ya.x + xa.y*ya.y + xa.z*ya.z + xa.w*ya.w
                            + xb.x*yb.x + xb.y*yb.y + xb.z*yb.z + xb.w*yb.w;
                    v += __shfl_xor(v, 1); v += __shfl_xor(v, 2);
                    v += __shfl_xor(v, 4); v += __shfl_xor(v, 8);
                    if (l16 == 0) ENCMAX(v, key, row);
                }
            }
            // overflow fallback: exact full rescan (rigor path, ~never)
            for (int rr = 0; rr < TROWS; ++rr) {
                if (rowOvf[p][rr]) {
                    const float* qp = q + (g0 + rr) * CDIM + l16 * 8;
                    float4 xa = *(const float4*)(qp), xb = *(const float4*)(qp + 4);
                    for (int it = 0; it < 16; ++it) {
                        int key = it * 64 + grp;
                        const float* kp2 = keys + (long)key * CDIM + l16 * 8;
                        float4 ya = *(const float4*)(kp2), yb = *(const float4*)(kp2 + 4);
                        float v = xa.x*ya.x + xa.y*ya.y + xa.z*ya.z + xa.w*ya.w
                                + xb.x*yb.x + xb.y*yb.y + xb.z*yb.z + xb.w*yb.w;
                        v += __shfl_xor(v, 1); v += __shfl_xor(v, 2);
                        v += __shfl_xor(v, 4); v += __shfl_xor(v, 8);
                        if (l16 == 0) ENCMAX(v, key, rr);
                    }
                }
            }
        }
        __syncthreads();                                   // B4
        if (t < TROWS) {
            if (rowOvf[p][t] || candCnt[p][t] != 1)
                rowIdxAll[tile * TROWS + t] =
                    1023 - (int)(unsigned)(rowBest[p][t] & 0xffffffffull);
        }
    }
    __syncthreads();

    // ---- batched gather: 4 passes x 64 rows, 16 lanes per row ----
    {
        int l16 = t & 15;
        #pragma unroll 1
        for (int pass = 0; pass < 4; ++pass) {
            int row = pass * 64 + (t >> 4);
            int idx = rowIdxAll[row];
            long g = blk0 + row;
            const float* qp  = q    + g * CDIM + l16 * 8;
            const float* kp2 = keys + (long)idx * CDIM + l16 * 8;
            const float* rp  = rep  + g * CDIM + l16 * 8;
            const float* vp  = vals + (long)idx * CDIM + l16 * 8;
            float4 qa = *(const float4*)(qp),  qb = *(const float4*)(qp + 4);
            float4 ka = *(const float4*)(kp2), kb4 = *(const float4*)(kp2 + 4);
            float4 ra = *(const float4*)(rp),  rb = *(const float4*)(rp + 4);
            float4 va = *(const float4*)(vp),  vb = *(const float4*)(vp + 4);
            float d0 = qa.x-ka.x, d1 = qa.y-ka.y, d2 = qa.z-ka.z, d3 = qa.w-ka.w;
            float d4 = qb.x-kb4.x, d5 = qb.y-kb4.y, d6 = qb.z-kb4.z, d7 = qb.w-kb4.w;
            float kg = d0*d0+d1*d1+d2*d2+d3*d3+d4*d4+d5*d5+d6*d6+d7*d7;
            float e0 = ra.x-va.x, e1 = ra.y-va.y, e2 = ra.z-va.z, e3 = ra.w-va.w;
            float e4 = rb.x-vb.x, e5 = rb.y-vb.y, e6 = rb.z-vb.z, e7 = rb.w-vb.w;
            float vg = e0*e0+e1*e1+e2*e2+e3*e3+e4*e4+e5*e5+e6*e6+e7*e7;
            kg += __shfl_xor(kg, 1); kg += __shfl_xor(kg, 2);
            kg += __shfl_xor(kg, 4); kg += __shfl_xor(kg, 8);
            vg += __shfl_xor(vg, 1); vg += __shfl_xor(vg, 2);
            vg += __shfl_xor(vg, 4); vg += __shfl_xor(vg, 8);
            if (l16 == 0) { out[g] = kg; out[NROWS + g] = vg; }
        }
    }
}

extern "C" void kernel_launch(void* const* d_in, const int* in_sizes, int n_in,
                              void* d_out, int out_size, void* d_ws, size_t ws_size,
                              hipStream_t stream) {
    const float* q    = (const float*)d_in[0];  // trend_representation
    const float* rep  = (const float*)d_in[1];  // representation
    const float* keys = (const float*)d_in[2];
    const float* vals = (const float*)d_in[3];
    _Float16* kh = (_Float16*)d_ws;             // 256 KB fp16 key cache (fragment order)

    cvt_keys_kernel<<<128, 256, 0, stream>>>(keys, kh);
    gather_main<<<NROWS / BROWS, 1024, 0, stream>>>(q, rep, keys, vals, kh,
                                                    (float*)d_out);
}

// Round 11
// 196.565 us; speedup vs baseline: 1.0962x; 1.0962x over previous
//
#include <hip/hip_runtime.h>

#define NROWS  65536
#define CDIM   128
#define MKEYS  1024
#define BROWS  64     // rows per block (4 blocks/CU -> cross-block TLP)
#define TROWS  16     // rows per tile
#define NTILES (BROWS / TROWS)
#define CANDCAP 32

typedef _Float16 half8 __attribute__((ext_vector_type(8)));
typedef _Float16 half4 __attribute__((ext_vector_type(4)));
typedef float    floatx4 __attribute__((ext_vector_type(4)));

union FU { float f; unsigned u; };

#define MFMA16 __builtin_amdgcn_mfma_f32_16x16x32_f16

// ---------------- Kernel A: convert keys fp32 -> fp16 in MFMA-fragment order --------
// Layout: for key k, dim d:  g=k>>4, n=k&15, f=d>>5, q8=(d&31)>>3, e=d&7
//   kh[ ((g*4+f)*64 + q8*16 + n)*8 + e ] = (fp16) keys[k][d]
// Fragment (g,f): kh + (g*4+f)*512 + lane*8  -> 64 lanes x 16B contiguous.
__global__ __launch_bounds__(256) void cvt_keys_kernel(const float* __restrict__ keys,
                                                       _Float16* __restrict__ kh) {
    int i  = blockIdx.x * 256 + threadIdx.x;        // 32768 threads
    int k  = i >> 5;                                // key 0..1023
    int d0 = (i & 31) * 4;                          // dim 0,4,...,124
    float4 f4 = *(const float4*)(keys + (long)k * CDIM + d0);
    half4 hv;
    hv[0] = (_Float16)f4.x; hv[1] = (_Float16)f4.y;
    hv[2] = (_Float16)f4.z; hv[3] = (_Float16)f4.w;
    int g = k >> 4, n = k & 15;
    int f = d0 >> 5, q8 = (d0 & 31) >> 3, e = d0 & 7;
    long idx = ((long)((g * 4 + f) * 64 + q8 * 16 + n)) * 8 + e;
    *(half4*)(kh + idx) = hv;
}

// ---------------- Kernel B: keys-in-registers, R9 codegen, 4 blocks/CU ---------------
// BODY IDENTICAL TO R9 (proven: VGPR=128, no spill, absmax 0.0, 115us rocprof).
// Only change: BROWS 256 -> 64 (grid 1024 = 4 blocks/CU). Cross-block overlap hides
// the per-tile latency chains a single block serializes on. 512 thr x 8 waves;
// each wave holds 128 keys (32 half8 = 128 VGPR) loaded once.
__global__ __launch_bounds__(512, 2) void gather_main(
    const float* __restrict__ q,      // trend_representation (65536x128)
    const float* __restrict__ rep,    // representation
    const float* __restrict__ keys,   // fp32 keys (1024x128)
    const float* __restrict__ vals,   // fp32 values
    const _Float16* __restrict__ kh,  // fp16 keys, fragment order (ws)
    float* __restrict__ out)          // [131072]: keys_g then values_g
{
    __shared__ _Float16 qh[TROWS][128];            // 4 KB, swizzled fp16 q-tile
    __shared__ float qss[TROWS][17];               // per-(row,c8) sumsq
    __shared__ float wtv[8][TROWS];                // per-wave per-row max
    __shared__ float rowT[TROWS];
    __shared__ int   candCnt[TROWS];
    __shared__ int   candKey[TROWS][CANDCAP];
    __shared__ int   rowNeed[TROWS];
    __shared__ int   rowOvf[TROWS];
    __shared__ unsigned long long rowBest[TROWS];
    __shared__ int   rowIdxAll[BROWS];

    const int t    = threadIdx.x;     // 0..511
    const int w    = t >> 6;          // wave 0..7 (owns keys w*128..w*128+127)
    const int lane = t & 63;
    const int n    = lane & 15;       // q-row (C col) in tile
    const int quad = lane >> 4;       // key sub-slice / C row group
    const long blk0 = (long)blockIdx.x * BROWS;

    // ---- preload this wave's 128 keys into 32 half8 registers (one burst) ----
    const _Float16* kb = kh + (long)w * 16384 + lane * 8;
#define KD(g) k##g##0, k##g##1, k##g##2, k##g##3
    half8 KD(0), KD(1), KD(2), KD(3), KD(4), KD(5), KD(6), KD(7);
#define KL(g) \
    k##g##0 = *(const half8*)(kb + ((g)*4 + 0) * 512); \
    k##g##1 = *(const half8*)(kb + ((g)*4 + 1) * 512); \
    k##g##2 = *(const half8*)(kb + ((g)*4 + 2) * 512); \
    k##g##3 = *(const half8*)(kb + ((g)*4 + 3) * 512);
    KL(0) KL(1) KL(2) KL(3) KL(4) KL(5) KL(6) KL(7)

#define ENCMAX(v_, key_, dst_) {                                           \
        FU su; su.f = (v_);                                                \
        unsigned ord = (su.u & 0x80000000u) ? ~su.u : (su.u | 0x80000000u);\
        unsigned long long enc = ((unsigned long long)ord << 32)           \
                               | (unsigned)(1023 - (key_));                \
        atomicMax(&rowBest[dst_], enc); }

    for (int tile = 0; tile < NTILES; ++tile) {
        const long g0 = blk0 + tile * TROWS;

        // ---- stage q-tile (waves 0-3) + reset row state (wave 4) ----
        if (t < 256) {
            int row = t >> 4, c8 = t & 15;
            const float4* src = (const float4*)(q + (g0 + row) * CDIM + c8 * 8);
            float4 a0 = src[0], a1 = src[1];
            qss[row][c8] = a0.x*a0.x + a0.y*a0.y + a0.z*a0.z + a0.w*a0.w
                         + a1.x*a1.x + a1.y*a1.y + a1.z*a1.z + a1.w*a1.w;
            half8 hv;
            hv[0] = (_Float16)a0.x; hv[1] = (_Float16)a0.y;
            hv[2] = (_Float16)a0.z; hv[3] = (_Float16)a0.w;
            hv[4] = (_Float16)a1.x; hv[5] = (_Float16)a1.y;
            hv[6] = (_Float16)a1.z; hv[7] = (_Float16)a1.w;
            int phys = c8 ^ (row & 7);
            *(half8*)&qh[row][phys * 8] = hv;
        } else if (t < 256 + TROWS) {
            int r = t - 256;
            candCnt[r] = 0; rowOvf[r] = 0; rowBest[r] = 0ull;
        }
        __syncthreads();

        // ---- B-fragments for row n (shared by both passes) ----
        int x = n & 7;
        half8 qf0 = *(const half8*)&qh[n][((0 * 4 + quad) ^ x) * 8];
        half8 qf1 = *(const half8*)&qh[n][((1 * 4 + quad) ^ x) * 8];
        half8 qf2 = *(const half8*)&qh[n][((2 * 4 + quad) ^ x) * 8];
        half8 qf3 = *(const half8*)&qh[n][((3 * 4 + quad) ^ x) * 8];

        // ---- pass 1: per-lane max over this wave's keys (value only) ----
        float m1 = -3.4e38f;
#define P1(g) { floatx4 acc = {0.f,0.f,0.f,0.f};                         \
        acc = MFMA16(k##g##0, qf0, acc, 0, 0, 0);                        \
        acc = MFMA16(k##g##1, qf1, acc, 0, 0, 0);                        \
        acc = MFMA16(k##g##2, qf2, acc, 0, 0, 0);                        \
        acc = MFMA16(k##g##3, qf3, acc, 0, 0, 0);                        \
        m1 = fmaxf(m1, fmaxf(fmaxf(acc[0], acc[1]), fmaxf(acc[2], acc[3]))); }
        P1(0) P1(1) P1(2) P1(3) P1(4) P1(5) P1(6) P1(7)
        // merge across quads (same row, disjoint keys)
        m1 = fmaxf(m1, __shfl_xor(m1, 16));
        m1 = fmaxf(m1, __shfl_xor(m1, 32));
        if (lane < TROWS) wtv[w][n] = m1;
        __syncthreads();

        // ---- threshold per row: thr = M1 - 2*e1 - slack ----
        if (t < TROWS) {
            float M1 = wtv[0][t];
            #pragma unroll
            for (int ww = 1; ww < 8; ++ww) M1 = fmaxf(M1, wtv[ww][t]);
            float qn2 = 0.f;
            #pragma unroll
            for (int j = 0; j < 16; ++j) qn2 += qss[t][j];
            // fp16 rounding: |s~ - s| <= 2^-10*1.01*||q||*||k||max(<=17) + slack
            float e1 = 0.0168f * sqrtf(qn2) + 0.002f;
            rowT[t] = M1 - 2.f * e1 - 0.02f;
        }
        __syncthreads();

        // ---- pass 2: bit-identical recompute; push ALL keys >= thr ----
        float thr = rowT[n];
#define PUSHK(K_) { int p = atomicAdd(&candCnt[n], 1);                   \
        if (p < CANDCAP) candKey[n][p] = (K_); else rowOvf[n] = 1; }
#define P2(g) { floatx4 acc = {0.f,0.f,0.f,0.f};                         \
        acc = MFMA16(k##g##0, qf0, acc, 0, 0, 0);                        \
        acc = MFMA16(k##g##1, qf1, acc, 0, 0, 0);                        \
        acc = MFMA16(k##g##2, qf2, acc, 0, 0, 0);                        \
        acc = MFMA16(k##g##3, qf3, acc, 0, 0, 0);                        \
        int keyb = ((w * 8 + (g)) << 4) + (quad << 2);                   \
        if (acc[0] >= thr) PUSHK(keyb);                                  \
        if (acc[1] >= thr) PUSHK(keyb + 1);                              \
        if (acc[2] >= thr) PUSHK(keyb + 2);                              \
        if (acc[3] >= thr) PUSHK(keyb + 3); }
        P2(0) P2(1) P2(2) P2(3) P2(4) P2(5) P2(6) P2(7)
        __syncthreads();

        // ---- resolve: sole candidate == exact argmax; else exact rescore ----
        if (t < TROWS) {
            int cnt = candCnt[t];
            if (!rowOvf[t] && cnt == 1) {
                rowIdxAll[tile * TROWS + t] = candKey[t][0];
                rowNeed[t] = 0;
            } else {
                rowNeed[t] = 1;
            }
        }
        __syncthreads();

        // ---- exact fp32 rescore: 32 groups of 16 lanes; coalesced 512B dots ----
        {
            int grp = t >> 4, l16 = t & 15;
            #pragma unroll 1
            for (int sweep = 0; sweep < 16; ++sweep) {
                int item = sweep * 32 + grp;       // (row, slot) = (item>>5, item&31)
                int row = item >> 5, slot = item & 31;
                if (rowNeed[row] && !rowOvf[row] && slot < candCnt[row]) {
                    int key = candKey[row][slot];
                    const float* qp  = q + (g0 + row) * CDIM + l16 * 8;
                    const float* kp2 = keys + (long)key * CDIM + l16 * 8;
                    float4 xa = *(const float4*)(qp),  xb = *(const float4*)(qp + 4);
                    float4 ya = *(const float4*)(kp2), yb = *(const float4*)(kp2 + 4);
                    float v = xa.x*ya.x + xa.y*ya.y + xa.z*ya.z + xa.w*ya.w
                            + xb.x*yb.x + xb.y*yb.y + xb.z*yb.z + xb.w*yb.w;
                    v += __shfl_xor(v, 1); v += __shfl_xor(v, 2);
                    v += __shfl_xor(v, 4); v += __shfl_xor(v, 8);
                    if (l16 == 0) ENCMAX(v, key, row);
                }
            }
            // overflow fallback: exact full rescan (rigor path, ~never)
            for (int rr = 0; rr < TROWS; ++rr) {
                if (rowOvf[rr]) {
                    const float* qp = q + (g0 + rr) * CDIM + l16 * 8;
                    float4 xa = *(const float4*)(qp), xb = *(const float4*)(qp + 4);
                    for (int it = 0; it < 32; ++it) {
                        int key = it * 32 + grp;
                        const float* kp2 = keys + (long)key * CDIM + l16 * 8;
                        float4 ya = *(const float4*)(kp2), yb = *(const float4*)(kp2 + 4);
                        float v = xa.x*ya.x + xa.y*ya.y + xa.z*ya.z + xa.w*ya.w
                                + xb.x*yb.x + xb.y*yb.y + xb.z*yb.z + xb.w*yb.w;
                        v += __shfl_xor(v, 1); v += __shfl_xor(v, 2);
                        v += __shfl_xor(v, 4); v += __shfl_xor(v, 8);
                        if (l16 == 0) ENCMAX(v, key, rr);
                    }
                }
            }
        }
        __syncthreads();
        if (t < TROWS && rowNeed[t]) {
            rowIdxAll[tile * TROWS + t] =
                1023 - (int)(unsigned)(rowBest[t] & 0xffffffffull);
        }
        __syncthreads();
    }

    // ---- batched gather: BROWS/32 passes x 32 rows, 16 lanes per row ----
    {
        int l16 = t & 15;
        #pragma unroll 1
        for (int pass = 0; pass < BROWS / 32; ++pass) {
            int row = pass * 32 + (t >> 4);
            int idx = rowIdxAll[row];
            long g = blk0 + row;
            const float* qp  = q    + g * CDIM + l16 * 8;
            const float* kp2 = keys + (long)idx * CDIM + l16 * 8;
            const float* rp  = rep  + g * CDIM + l16 * 8;
            const float* vp  = vals + (long)idx * CDIM + l16 * 8;
            float4 qa = *(const float4*)(qp),  qb = *(const float4*)(qp + 4);
            float4 ka = *(const float4*)(kp2), kb4 = *(const float4*)(kp2 + 4);
            float4 ra = *(const float4*)(rp),  rb = *(const float4*)(rp + 4);
            float4 va = *(const float4*)(vp),  vb = *(const float4*)(vp + 4);
            float d0 = qa.x-ka.x, d1 = qa.y-ka.y, d2 = qa.z-ka.z, d3 = qa.w-ka.w;
            float d4 = qb.x-kb4.x, d5 = qb.y-kb4.y, d6 = qb.z-kb4.z, d7 = qb.w-kb4.w;
            float kg = d0*d0+d1*d1+d2*d2+d3*d3+d4*d4+d5*d5+d6*d6+d7*d7;
            float e0 = ra.x-va.x, e1 = ra.y-va.y, e2 = ra.z-va.z, e3 = ra.w-va.w;
            float e4 = rb.x-vb.x, e5 = rb.y-vb.y, e6 = rb.z-vb.z, e7 = rb.w-vb.w;
            float vg = e0*e0+e1*e1+e2*e2+e3*e3+e4*e4+e5*e5+e6*e6+e7*e7;
            kg += __shfl_xor(kg, 1); kg += __shfl_xor(kg, 2);
            kg += __shfl_xor(kg, 4); kg += __shfl_xor(kg, 8);
            vg += __shfl_xor(vg, 1); vg += __shfl_xor(vg, 2);
            vg += __shfl_xor(vg, 4); vg += __shfl_xor(vg, 8);
            if (l16 == 0) { out[g] = kg; out[NROWS + g] = vg; }
        }
    }
}

extern "C" void kernel_launch(void* const* d_in, const int* in_sizes, int n_in,
                              void* d_out, int out_size, void* d_ws, size_t ws_size,
                              hipStream_t stream) {
    const float* q    = (const float*)d_in[0];  // trend_representation
    const float* rep  = (const float*)d_in[1];  // representation
    const float* keys = (const float*)d_in[2];
    const float* vals = (const float*)d_in[3];
    _Float16* kh = (_Float16*)d_ws;             // 256 KB fp16 key cache (fragment order)

    cvt_keys_kernel<<<128, 256, 0, stream>>>(keys, kh);
    gather_main<<<NROWS / BROWS, 512, 0, stream>>>(q, rep, keys, vals, kh,
                                                   (float*)d_out);
}

// Round 12
// 161.524 us; speedup vs baseline: 1.3340x; 1.2169x over previous
//
#include <hip/hip_runtime.h>

#define NROWS  65536
#define CDIM   128
#define MKEYS  1024
#define BROWS  256    // rows per block (1 block/CU -- proven residency)
#define TROWS  16
#define NPAIRS 8      // 8 pairs x 32 rows
#define CANDCAP 8

typedef _Float16 half8 __attribute__((ext_vector_type(8)));
typedef _Float16 half4 __attribute__((ext_vector_type(4)));
typedef float    floatx4 __attribute__((ext_vector_type(4)));

union FU { float f; unsigned u; };

#define MFMA16 __builtin_amdgcn_mfma_f32_16x16x32_f16

// ---------------- Kernel A: convert keys fp32 -> fp16 in MFMA-fragment order --------
// Layout: for key k, dim d:  g=k>>4, n=k&15, f=d>>5, q8=(d&31)>>3, e=d&7
//   kh[ ((g*4+f)*64 + q8*16 + n)*8 + e ] = (fp16) keys[k][d]
// Fragment (g,f): kh + (g*4+f)*512 + lane*8  -> 64 lanes x 16B contiguous.
__global__ __launch_bounds__(256) void cvt_keys_kernel(const float* __restrict__ keys,
                                                       _Float16* __restrict__ kh) {
    int i  = blockIdx.x * 256 + threadIdx.x;        // 32768 threads
    int k  = i >> 5;                                // key 0..1023
    int d0 = (i & 31) * 4;                          // dim 0,4,...,124
    float4 f4 = *(const float4*)(keys + (long)k * CDIM + d0);
    half4 hv;
    hv[0] = (_Float16)f4.x; hv[1] = (_Float16)f4.y;
    hv[2] = (_Float16)f4.z; hv[3] = (_Float16)f4.w;
    int g = k >> 4, n = k & 15;
    int f = d0 >> 5, q8 = (d0 & 31) >> 3, e = d0 & 7;
    long idx = ((long)((g * 4 + f) * 64 + q8 * 16 + n)) * 8 + e;
    *(half4*)(kh + idx) = hv;
}

// ---------------- Kernel B: keys-in-registers, tile-PAIR pipeline (R12) --------------
// Same register environment as R9 (512 thr, launch_bounds(512,2), 32 named key half8
// = 128 VGPR, loaded once; VGPR cap at this bound is 256 so no spill pressure).
// Per pair of 16-row tiles (32 rows): all-wave staging, pass1 (64 MFMA slab) -> M1,
// redundant per-thread threshold thr = M1-2e1-slack, pass2 (64 MFMA slab) pushes ALL
// keys >= thr, ballot-gated sparse exact-rescore / full-rescan. 4 barriers / 32 rows
// (R9: 12). Rigor: argmax satisfies s~ >= thr so it's always in the candidate list;
// cnt==1 -> done; cnt>1 -> exact fp32 rescore (lowest-key ties); >CANDCAP -> rescan.
__global__ __launch_bounds__(512, 2) void gather_main(
    const float* __restrict__ q,      // trend_representation (65536x128)
    const float* __restrict__ rep,    // representation
    const float* __restrict__ keys,   // fp32 keys (1024x128)
    const float* __restrict__ vals,   // fp32 values
    const _Float16* __restrict__ kh,  // fp16 keys, fragment order (ws)
    float* __restrict__ out)          // [131072]: keys_g then values_g
{
    __shared__ _Float16 qh[2][TROWS][128];         // 8 KB: tile A / tile B
    __shared__ float qss[2][TROWS][17];
    __shared__ float wtv[8][2][TROWS];             // per-wave per-row max
    __shared__ int   candCnt[32];                  // r = tile*16 + row
    __shared__ int   candKey[32][CANDCAP];
    __shared__ int   rowOvf[32];
    __shared__ unsigned long long rowBest[32];
    __shared__ int   rowIdxAll[BROWS];

    const int t    = threadIdx.x;     // 0..511
    const int w    = t >> 6;          // wave 0..7 (owns keys w*128..w*128+127)
    const int lane = t & 63;
    const int n    = lane & 15;       // q-row (C col) in tile
    const int quad = lane >> 4;       // key sub-slice / C row group
    const long blk0 = (long)blockIdx.x * BROWS;

    // ---- preload this wave's 128 keys into 32 half8 registers (one burst) ----
    const _Float16* kb = kh + (long)w * 16384 + lane * 8;
#define KD(g) k##g##0, k##g##1, k##g##2, k##g##3
    half8 KD(0), KD(1), KD(2), KD(3), KD(4), KD(5), KD(6), KD(7);
#define KL(g) \
    k##g##0 = *(const half8*)(kb + ((g)*4 + 0) * 512); \
    k##g##1 = *(const half8*)(kb + ((g)*4 + 1) * 512); \
    k##g##2 = *(const half8*)(kb + ((g)*4 + 2) * 512); \
    k##g##3 = *(const half8*)(kb + ((g)*4 + 3) * 512);
    KL(0) KL(1) KL(2) KL(3) KL(4) KL(5) KL(6) KL(7)

#define ENCMAX(v_, key_, r_) {                                             \
        FU su; su.f = (v_);                                                \
        unsigned ord = (su.u & 0x80000000u) ? ~su.u : (su.u | 0x80000000u);\
        unsigned long long enc = ((unsigned long long)ord << 32)           \
                               | (unsigned)(1023 - (key_));                \
        atomicMax(&rowBest[r_], enc); }

    for (int pair = 0; pair < NPAIRS; ++pair) {
        const long g0 = blk0 + (long)pair * 32;    // rows g0..g0+31 (A:0-15, B:16-31)

        // ---- stage BOTH tiles (waves 0-3 -> A, 4-7 -> B) + reset pair state ----
        {
            int half = t >> 8, tt = t & 255;
            int row = tt >> 4, c8 = tt & 15;
            const float4* src =
                (const float4*)(q + (g0 + half * TROWS + row) * CDIM + c8 * 8);
            float4 a0 = src[0], a1 = src[1];
            qss[half][row][c8] = a0.x*a0.x + a0.y*a0.y + a0.z*a0.z + a0.w*a0.w
                               + a1.x*a1.x + a1.y*a1.y + a1.z*a1.z + a1.w*a1.w;
            half8 hv;
            hv[0] = (_Float16)a0.x; hv[1] = (_Float16)a0.y;
            hv[2] = (_Float16)a0.z; hv[3] = (_Float16)a0.w;
            hv[4] = (_Float16)a1.x; hv[5] = (_Float16)a1.y;
            hv[6] = (_Float16)a1.z; hv[7] = (_Float16)a1.w;
            int phys = c8 ^ (row & 7);
            *(half8*)&qh[half][row][phys * 8] = hv;
            if (t < 32) { candCnt[t] = 0; rowOvf[t] = 0; rowBest[t] = 0ull; }
        }
        __syncthreads();                                               // B1

        // ---- B-fragments for row n of both tiles ----
        int x = n & 7;
        int p0 = ((0 * 4 + quad) ^ x) * 8;
        int p1 = ((1 * 4 + quad) ^ x) * 8;
        int p2 = ((2 * 4 + quad) ^ x) * 8;
        int p3 = ((3 * 4 + quad) ^ x) * 8;
        half8 qfA0 = *(const half8*)&qh[0][n][p0];
        half8 qfA1 = *(const half8*)&qh[0][n][p1];
        half8 qfA2 = *(const half8*)&qh[0][n][p2];
        half8 qfA3 = *(const half8*)&qh[0][n][p3];
        half8 qfB0 = *(const half8*)&qh[1][n][p0];
        half8 qfB1 = *(const half8*)&qh[1][n][p1];
        half8 qfB2 = *(const half8*)&qh[1][n][p2];
        half8 qfB3 = *(const half8*)&qh[1][n][p3];

        // ---- pass 1: 64-MFMA slab over both tiles; per-lane max ----
        float m1A = -3.4e38f, m1B = -3.4e38f;
#define P1AB(g) {                                                            \
        floatx4 aA = {0.f,0.f,0.f,0.f}, aB = {0.f,0.f,0.f,0.f};              \
        aA = MFMA16(k##g##0, qfA0, aA, 0, 0, 0);                             \
        aB = MFMA16(k##g##0, qfB0, aB, 0, 0, 0);                             \
        aA = MFMA16(k##g##1, qfA1, aA, 0, 0, 0);                             \
        aB = MFMA16(k##g##1, qfB1, aB, 0, 0, 0);                             \
        aA = MFMA16(k##g##2, qfA2, aA, 0, 0, 0);                             \
        aB = MFMA16(k##g##2, qfB2, aB, 0, 0, 0);                             \
        aA = MFMA16(k##g##3, qfA3, aA, 0, 0, 0);                             \
        aB = MFMA16(k##g##3, qfB3, aB, 0, 0, 0);                             \
        m1A = fmaxf(m1A, fmaxf(fmaxf(aA[0], aA[1]), fmaxf(aA[2], aA[3])));   \
        m1B = fmaxf(m1B, fmaxf(fmaxf(aB[0], aB[1]), fmaxf(aB[2], aB[3]))); }
        P1AB(0) P1AB(1) P1AB(2) P1AB(3) P1AB(4) P1AB(5) P1AB(6) P1AB(7)
        m1A = fmaxf(m1A, __shfl_xor(m1A, 16));
        m1A = fmaxf(m1A, __shfl_xor(m1A, 32));
        m1B = fmaxf(m1B, __shfl_xor(m1B, 16));
        m1B = fmaxf(m1B, __shfl_xor(m1B, 32));
        if (lane < TROWS) { wtv[w][0][n] = m1A; wtv[w][1][n] = m1B; }
        __syncthreads();                                               // B2

        // ---- thresholds, computed redundantly by every thread for its row n ----
        float M1A = wtv[0][0][n], M1B = wtv[0][1][n];
        #pragma unroll
        for (int ww = 1; ww < 8; ++ww) {
            M1A = fmaxf(M1A, wtv[ww][0][n]);
            M1B = fmaxf(M1B, wtv[ww][1][n]);
        }
        float qn2A = 0.f, qn2B = 0.f;
        #pragma unroll
        for (int j = 0; j < 16; ++j) { qn2A += qss[0][n][j]; qn2B += qss[1][n][j]; }
        // fp16 rounding: |s~ - s| <= 2^-10*1.01*||q||*||k||max(<=17) + slack
        float thrA = M1A - 2.f * (0.0168f * sqrtf(qn2A) + 0.002f) - 0.02f;
        float thrB = M1B - 2.f * (0.0168f * sqrtf(qn2B) + 0.002f) - 0.02f;

        // ---- pass 2: bit-identical recompute; push ALL keys >= thr ----
#define PUSHK(r_, K_) { int pp_ = atomicAdd(&candCnt[r_], 1);                \
        if (pp_ < CANDCAP) candKey[r_][pp_] = (K_); else rowOvf[r_] = 1; }
#define P2AB(g) {                                                            \
        floatx4 aA = {0.f,0.f,0.f,0.f}, aB = {0.f,0.f,0.f,0.f};              \
        aA = MFMA16(k##g##0, qfA0, aA, 0, 0, 0);                             \
        aB = MFMA16(k##g##0, qfB0, aB, 0, 0, 0);                             \
        aA = MFMA16(k##g##1, qfA1, aA, 0, 0, 0);                             \
        aB = MFMA16(k##g##1, qfB1, aB, 0, 0, 0);                             \
        aA = MFMA16(k##g##2, qfA2, aA, 0, 0, 0);                             \
        aB = MFMA16(k##g##2, qfB2, aB, 0, 0, 0);                             \
        aA = MFMA16(k##g##3, qfA3, aA, 0, 0, 0);                             \
        aB = MFMA16(k##g##3, qfB3, aB, 0, 0, 0);                             \
        int keyb = ((w * 8 + (g)) << 4) + (quad << 2);                       \
        if (aA[0] >= thrA) PUSHK(n, keyb);                                   \
        if (aA[1] >= thrA) PUSHK(n, keyb + 1);                               \
        if (aA[2] >= thrA) PUSHK(n, keyb + 2);                               \
        if (aA[3] >= thrA) PUSHK(n, keyb + 3);                               \
        if (aB[0] >= thrB) PUSHK(16 + n, keyb);                              \
        if (aB[1] >= thrB) PUSHK(16 + n, keyb + 1);                          \
        if (aB[2] >= thrB) PUSHK(16 + n, keyb + 2);                          \
        if (aB[3] >= thrB) PUSHK(16 + n, keyb + 3); }
        P2AB(0) P2AB(1) P2AB(2) P2AB(3) P2AB(4) P2AB(5) P2AB(6) P2AB(7)
        __syncthreads();                                               // B3

        // ---- ballot-gated sparse exact resolve ----
        {
            int r32 = lane & 31;
            int cntL = candCnt[r32], ovL = rowOvf[r32];
            unsigned long long needMask =
                __ballot(!ovL && cntL > 1) & 0xffffffffull;
            unsigned long long ovfMask =
                __ballot(ovL != 0) & 0xffffffffull;
            // multi-candidate rows: wave w rescores slot w (64-lane coalesced dot)
            while (needMask) {
                int rb = __builtin_ctzll(needMask); needMask &= needMask - 1;
                int cnt2 = candCnt[rb];
                if (w < cnt2) {
                    int key = candKey[rb][w];
                    const float2 xq = *(const float2*)(q + (g0 + rb) * CDIM + lane * 2);
                    const float2 xk = *(const float2*)(keys + (long)key * CDIM + lane * 2);
                    float v = xq.x * xk.x + xq.y * xk.y;
                    v += __shfl_xor(v, 1);  v += __shfl_xor(v, 2);
                    v += __shfl_xor(v, 4);  v += __shfl_xor(v, 8);
                    v += __shfl_xor(v, 16); v += __shfl_xor(v, 32);
                    if (lane == 0) ENCMAX(v, key, rb);
                }
            }
            // overflow rows: exact full rescan (rigor path, ~never)
            while (ovfMask) {
                int rb = __builtin_ctzll(ovfMask); ovfMask &= ovfMask - 1;
                int grp = t >> 4, l16 = t & 15;
                const float* qp = q + (g0 + rb) * CDIM + l16 * 8;
                float4 xa = *(const float4*)(qp), xb = *(const float4*)(qp + 4);
                for (int it = 0; it < 32; ++it) {
                    int key = it * 32 + grp;
                    const float* kp2 = keys + (long)key * CDIM + l16 * 8;
                    float4 ya = *(const float4*)(kp2), yb = *(const float4*)(kp2 + 4);
                    float v = xa.x*ya.x + xa.y*ya.y + xa.z*ya.z + xa.w*ya.w
                            + xb.x*yb.x + xb.y*yb.y + xb.z*yb.z + xb.w*yb.w;
                    v += __shfl_xor(v, 1); v += __shfl_xor(v, 2);
                    v += __shfl_xor(v, 4); v += __shfl_xor(v, 8);
                    if (l16 == 0) ENCMAX(v, key, rb);
                }
            }
        }
        __syncthreads();                                               // B4

        // ---- decode 32 rows ----
        if (t < 32) {
            int cnt = candCnt[t];
            rowIdxAll[pair * 32 + t] =
                (!rowOvf[t] && cnt == 1)
                    ? candKey[t][0]
                    : (1023 - (int)(unsigned)(rowBest[t] & 0xffffffffull));
        }
    }
    __syncthreads();

    // ---- batched gather: 8 passes x 32 rows, 16 lanes per row ----
    {
        int l16 = t & 15;
        #pragma unroll 1
        for (int pass = 0; pass < BROWS / 32; ++pass) {
            int row = pass * 32 + (t >> 4);
            int idx = rowIdxAll[row];
            long g = blk0 + row;
            const float* qp  = q    + g * CDIM + l16 * 8;
            const float* kp2 = keys + (long)idx * CDIM + l16 * 8;
            const float* rp  = rep  + g * CDIM + l16 * 8;
            const float* vp  = vals + (long)idx * CDIM + l16 * 8;
            float4 qa = *(const float4*)(qp),  qb = *(const float4*)(qp + 4);
            float4 ka = *(const float4*)(kp2), kb4 = *(const float4*)(kp2 + 4);
            float4 ra = *(const float4*)(rp),  rb = *(const float4*)(rp + 4);
            float4 va = *(const float4*)(vp),  vb = *(const float4*)(vp + 4);
            float d0 = qa.x-ka.x, d1 = qa.y-ka.y, d2 = qa.z-ka.z, d3 = qa.w-ka.w;
            float d4 = qb.x-kb4.x, d5 = qb.y-kb4.y, d6 = qb.z-kb4.z, d7 = qb.w-kb4.w;
            float kg = d0*d0+d1*d1+d2*d2+d3*d3+d4*d4+d5*d5+d6*d6+d7*d7;
            float e0 = ra.x-va.x, e1 = ra.y-va.y, e2 = ra.z-va.z, e3 = ra.w-va.w;
            float e4 = rb.x-vb.x, e5 = rb.y-vb.y, e6 = rb.z-vb.z, e7 = rb.w-vb.w;
            float vg = e0*e0+e1*e1+e2*e2+e3*e3+e4*e4+e5*e5+e6*e6+e7*e7;
            kg += __shfl_xor(kg, 1); kg += __shfl_xor(kg, 2);
            kg += __shfl_xor(kg, 4); kg += __shfl_xor(kg, 8);
            vg += __shfl_xor(vg, 1); vg += __shfl_xor(vg, 2);
            vg += __shfl_xor(vg, 4); vg += __shfl_xor(vg, 8);
            if (l16 == 0) { out[g] = kg; out[NROWS + g] = vg; }
        }
    }
}

extern "C" void kernel_launch(void* const* d_in, const int* in_sizes, int n_in,
                              void* d_out, int out_size, void* d_ws, size_t ws_size,
                              hipStream_t stream) {
    const float* q    = (const float*)d_in[0];  // trend_representation
    const float* rep  = (const float*)d_in[1];  // representation
    const float* keys = (const float*)d_in[2];
    const float* vals = (const float*)d_in[3];
    _Float16* kh = (_Float16*)d_ws;             // 256 KB fp16 key cache (fragment order)

    cvt_keys_kernel<<<128, 256, 0, stream>>>(keys, kh);
    gather_main<<<NROWS / BROWS, 512, 0, stream>>>(q, rep, keys, vals, kh,
                                                   (float*)d_out);
}